// Round 4
// baseline (1080.359 us; speedup 1.0000x reference)
//
#include <hip/hip_runtime.h>

#define N_NODES 50000
#define N_EDGES 800000
#define DIM 256
#define HEADS 8
#define HEAD_DIM 32
#define NEG_SLOPE 0.2f

typedef unsigned short u16;
typedef float floatx4 __attribute__((ext_vector_type(4)));
typedef __bf16 bf16x8 __attribute__((ext_vector_type(8)));

__device__ __forceinline__ float b2f(u16 u) {
    union { unsigned int i; float f; } v; v.i = ((unsigned int)u) << 16; return v.f;
}
// float -> bf16 (RNE), NaN-preserving (quiet)
__device__ __forceinline__ u16 f2b(float f) {
    union { float f; unsigned int i; } v; v.f = f;
    unsigned int x = v.i;
    if ((x & 0x7f800000u) == 0x7f800000u && (x & 0x007fffffu)) {
        return (u16)((x >> 16) | 0x0040u);
    }
    unsigned int r = (x + 0x7fffu + ((x >> 16) & 1u)) >> 16;
    return (u16)r;
}

// ---------------- dtype detection ----------------
// fp32 data read as u16 pairs: low halves have uniform exponent bits ->
// ~56% decode to |x|>2^14 or 0<|x|<2^-100 as bf16. Real bf16 N(0,1): ~0%.
__global__ __launch_bounds__(256) void detect_dtype(const unsigned int* __restrict__ d,
                                                    int* __restrict__ flag) {
    __shared__ int cnt;
    if (threadIdx.x == 0) cnt = 0;
    __syncthreads();
    unsigned int w = d[threadIdx.x];
    int bad = 0;
    #pragma unroll
    for (int half = 0; half < 2; ++half) {
        u16 u = (u16)(w >> (16 * half));
        unsigned int e = (u >> 7) & 0xFFu;
        if (u != 0 && (e >= 141u || e <= 27u)) bad = 1;
    }
    atomicAdd(&cnt, bad);
    __syncthreads();
    if (threadIdx.x == 0) *flag = (cnt > 64) ? 1 : 0;   // 1 = fp32 inputs
}

// ---------------- diagnostic fill (ws too small signature ~100.0) ----------------
__global__ __launch_bounds__(256) void fill_u32(unsigned int* __restrict__ p,
                                                unsigned int v, int n) {
    int i = blockIdx.x * 256 + threadIdx.x;
    if (i < n) p[i] = v;
}

// ---------------- CSR build ----------------
__global__ __launch_bounds__(256) void zero_i32(int* __restrict__ p, int n) {
    int i = blockIdx.x * 256 + threadIdx.x;
    if (i < n) p[i] = 0;
}

__global__ __launch_bounds__(256) void hist_kernel(const int* __restrict__ dst,
                                                   int* __restrict__ counts, int E) {
    int i = blockIdx.x * 256 + threadIdx.x;
    if (i < E) {
        int d = dst[i];
        if (d >= 0 && d < N_NODES) atomicAdd(&counts[d], 1);
    }
}

__global__ __launch_bounds__(1024) void scan_kernel(const int* __restrict__ counts,
                                                    int* __restrict__ row_ptr,
                                                    int* __restrict__ wptr, int n) {
    __shared__ int buf[1024];
    __shared__ int carry_s;
    int tid = threadIdx.x;
    if (tid == 0) carry_s = 0;
    __syncthreads();
    for (int base = 0; base < n; base += 1024) {
        int i = base + tid;
        int v = (i < n) ? counts[i] : 0;
        buf[tid] = v;
        __syncthreads();
        for (int off = 1; off < 1024; off <<= 1) {
            int t = (tid >= off) ? buf[tid - off] : 0;
            __syncthreads();
            buf[tid] += t;
            __syncthreads();
        }
        int incl = buf[tid];
        int carry = carry_s;
        if (i < n) {
            int rp = carry + incl - v;
            row_ptr[i] = rp;
            wptr[i] = rp;
        }
        __syncthreads();
        if (tid == 0) carry_s = carry + buf[1023];
        __syncthreads();
    }
    if (tid == 0) row_ptr[n] = carry_s;
}

__global__ __launch_bounds__(256) void scatter_kernel(const int* __restrict__ src,
                                                      const int* __restrict__ dst,
                                                      int* __restrict__ wptr,
                                                      int* __restrict__ src_sorted, int E) {
    int i = blockIdx.x * 256 + threadIdx.x;
    if (i < E) {
        int d = dst[i];
        if (d < 0 || d >= N_NODES) return;
        int pos = atomicAdd(&wptr[d], 1);
        if (pos >= 0 && pos < E) src_sorted[pos] = src[i];
    }
}

// ---- GEMM: out[M,256] = A[M,256] @ W[256,256], adaptive-in, bf16 LDS, fp32 acc ----

#define LDA 264
#define LDB 40

// a_mode/w_mode: 0 = input is bf16 always, 2 = fp32 iff *flagp
__global__ __launch_bounds__(256, 2) void gemm_bf16(const void* __restrict__ A,
                                                    const void* __restrict__ W,
                                                    u16* __restrict__ out, int M,
                                                    int a_mode, int w_mode,
                                                    const int* __restrict__ flagp) {
    __shared__ u16 As[64][LDA];
    __shared__ u16 Ws[256][LDB];
    const int tid  = threadIdx.x;
    const int wave = tid >> 6;
    const int lane = tid & 63;
    const int quad = lane >> 4;
    const int l16  = lane & 15;
    const int m0   = blockIdx.x * 64;
    const int isf  = *flagp;
    const bool a_fp32 = (a_mode == 2) && isf;
    const bool w_fp32 = (w_mode == 2) && isf;

    #pragma unroll
    for (int it = 0; it < 8; ++it) {
        int idx = it * 256 + tid;
        int r = idx >> 5;
        int c = (idx & 31) << 3;
        int gr = m0 + r;
        if (gr < M) {
            if (a_fp32) {
                const float* Af = (const float*)A;
                float4 f0 = *(const float4*)(Af + gr * 256 + c);
                float4 f1 = *(const float4*)(Af + gr * 256 + c + 4);
                As[r][c + 0] = f2b(f0.x); As[r][c + 1] = f2b(f0.y);
                As[r][c + 2] = f2b(f0.z); As[r][c + 3] = f2b(f0.w);
                As[r][c + 4] = f2b(f1.x); As[r][c + 5] = f2b(f1.y);
                As[r][c + 6] = f2b(f1.z); As[r][c + 7] = f2b(f1.w);
            } else {
                *(uint4*)&As[r][c] = *(const uint4*)((const u16*)A + gr * 256 + c);
            }
        } else {
            uint4 z = {0u, 0u, 0u, 0u};
            *(uint4*)&As[r][c] = z;
        }
    }

    floatx4 acc[16] = {};

    for (int s = 0; s < 8; ++s) {
        const int k0 = s * 32;
        __syncthreads();
        #pragma unroll
        for (int it = 0; it < 4; ++it) {
            int idx = it * 256 + tid;
            int kk = idx >> 5;
            int n8 = (idx & 31) << 3;
            u16 tmp[8];
            if (w_fp32) {
                const float* Wf = (const float*)W;
                float4 f0 = *(const float4*)(Wf + (k0 + kk) * 256 + n8);
                float4 f1 = *(const float4*)(Wf + (k0 + kk) * 256 + n8 + 4);
                tmp[0] = f2b(f0.x); tmp[1] = f2b(f0.y); tmp[2] = f2b(f0.z); tmp[3] = f2b(f0.w);
                tmp[4] = f2b(f1.x); tmp[5] = f2b(f1.y); tmp[6] = f2b(f1.z); tmp[7] = f2b(f1.w);
            } else {
                *(uint4*)tmp = *(const uint4*)((const u16*)W + (k0 + kk) * 256 + n8);
            }
            #pragma unroll
            for (int j = 0; j < 8; ++j) Ws[n8 + j][kk] = tmp[j];
        }
        __syncthreads();

        bf16x8 afrag = *(const bf16x8*)&As[wave * 16 + l16][k0 + quad * 8];
        #pragma unroll
        for (int t = 0; t < 16; ++t) {
            bf16x8 bfrag = *(const bf16x8*)&Ws[t * 16 + l16][quad * 8];
            acc[t] = __builtin_amdgcn_mfma_f32_16x16x32_bf16(afrag, bfrag, acc[t], 0, 0, 0);
        }
    }

    #pragma unroll
    for (int t = 0; t < 16; ++t) {
        #pragma unroll
        for (int r = 0; r < 4; ++r) {
            int grow = m0 + wave * 16 + quad * 4 + r;
            if (grow < M) out[grow * 256 + t * 16 + l16] = f2b(acc[t][r]);
        }
    }
}

// ---------------- el/er per (node, head); feat is internal bf16 ----------------

__global__ __launch_bounds__(256) void elr_kernel(const u16* __restrict__ feat,
                                                  const void* __restrict__ al,
                                                  const void* __restrict__ ar,
                                                  float* __restrict__ el,
                                                  float* __restrict__ er, int N,
                                                  const int* __restrict__ flagp) {
    int gid = blockIdx.x * 256 + threadIdx.x;
    if (gid >= N * HEADS) return;
    const int isf = *flagp;
    int n = gid >> 3, h = gid & 7;
    const u16* f = feat + n * DIM + h * HEAD_DIM;
    float sl = 0.f, sr = 0.f;
    #pragma unroll
    for (int d = 0; d < HEAD_DIM; ++d) {
        float fv = b2f(f[d]);
        float a1 = isf ? ((const float*)al)[h * HEAD_DIM + d] : b2f(((const u16*)al)[h * HEAD_DIM + d]);
        float a2 = isf ? ((const float*)ar)[h * HEAD_DIM + d] : b2f(((const u16*)ar)[h * HEAD_DIM + d]);
        sl += fv * a1;
        sr += fv * a2;
    }
    el[gid] = sl;
    er[gid] = sr;
}

// ---------------- per-dst softmax + aggregate ----------------
// out_mode: 0 = write bf16 always (internal h1), 2 = final output (fp32 iff *flagp)

__global__ __launch_bounds__(256) void aggregate_kernel(const u16* __restrict__ feat,
                                                        const float* __restrict__ el,
                                                        const float* __restrict__ er,
                                                        const void* __restrict__ bias,
                                                        const int* __restrict__ row_ptr,
                                                        const int* __restrict__ src_sorted,
                                                        void* __restrict__ out, int N,
                                                        int out_mode,
                                                        const int* __restrict__ flagp) {
    int n = blockIdx.x;
    int tid = threadIdx.x;
    int h = tid >> 5;
    int l32 = tid & 31;
    const int isf = *flagp;
    int beg = row_ptr[n], end = row_ptr[n + 1];
    beg = beg < 0 ? 0 : (beg > N_EDGES ? N_EDGES : beg);
    end = end < beg ? beg : (end > N_EDGES ? N_EDGES : end);
    int deg = end - beg;
    __shared__ float m_s[HEADS], li_s[HEADS];

    float ern = er[n * HEADS + h];

    float mx = -__builtin_inff();
    for (int i = l32; i < deg; i += 32) {
        int s = src_sorted[beg + i];
        s = s < 0 ? 0 : (s >= N_NODES ? N_NODES - 1 : s);
        float e = el[s * HEADS + h] + ern;
        e = e > 0.f ? e : NEG_SLOPE * e;
        mx = fmaxf(mx, e);
    }
    #pragma unroll
    for (int off = 16; off; off >>= 1) mx = fmaxf(mx, __shfl_xor(mx, off));

    float sm = 0.f;
    for (int i = l32; i < deg; i += 32) {
        int s = src_sorted[beg + i];
        s = s < 0 ? 0 : (s >= N_NODES ? N_NODES - 1 : s);
        float e = el[s * HEADS + h] + ern;
        e = e > 0.f ? e : NEG_SLOPE * e;
        sm += __expf(e - mx);
    }
    #pragma unroll
    for (int off = 16; off; off >>= 1) sm += __shfl_xor(sm, off);

    if (l32 == 0) {
        m_s[h] = mx;
        li_s[h] = sm > 0.f ? 1.f / sm : 0.f;
    }
    __syncthreads();
    float mh = m_s[h], inv = li_s[h];

    float acc = 0.f;
    for (int i = 0; i < deg; ++i) {
        int s = src_sorted[beg + i];
        s = s < 0 ? 0 : (s >= N_NODES ? N_NODES - 1 : s);
        float e = el[s * HEADS + h] + ern;
        e = e > 0.f ? e : NEG_SLOPE * e;
        float alpha = __expf(e - mh) * inv;
        acc += alpha * b2f(feat[s * DIM + tid]);
    }
    float bv = isf ? ((const float*)bias)[tid] : b2f(((const u16*)bias)[tid]);
    float o = acc + bv;
    o = (o > 0.f || !(o == o)) ? o : 0.f;   // NaN-preserving ReLU (tripwire)

    int idx = n * DIM + tid;
    if (out_mode == 0) {
        ((u16*)out)[idx] = f2b(o);
    } else if (isf) {
        ((float*)out)[idx] = o;
    } else {
        ((u16*)out)[idx] = f2b(o);
    }
}

// ---------------- launch ----------------

extern "C" void kernel_launch(void* const* d_in, const int* in_sizes, int n_in,
                              void* d_out, int out_size, void* d_ws, size_t ws_size,
                              hipStream_t stream) {
    const void* data = d_in[0];
    const int* src = (const int*)d_in[1];
    const int* dst = (const int*)d_in[2];
    const void* W1  = d_in[3];
    const void* al1 = d_in[4];
    const void* ar1 = d_in[5];
    const void* b1  = d_in[6];
    const void* W2  = d_in[7];
    const void* al2 = d_in[8];
    const void* ar2 = d_in[9];
    const void* b2  = d_in[10];

    const size_t NEEDED =
        (size_t)N_NODES * DIM * 2 +        // feat (bf16)
        (size_t)N_NODES * HEADS * 4 * 2 +  // el + er
        (size_t)N_NODES * 4 * 2 +          // counts, wptr
        (size_t)(N_NODES + 4) * 4 +        // row_ptr
        (size_t)N_EDGES * 4 +              // src_sorted
        256;                               // flag

    if (ws_size < NEEDED) {
        int nwords = (out_size + 1) / 2;
        fill_u32<<<(nwords + 255) / 256, 256, 0, stream>>>(
            (unsigned int*)d_out, 0x42C842C8u, nwords);
        return;
    }

    char* ws = (char*)d_ws;
    u16* feat = (u16*)ws;        ws += (size_t)N_NODES * DIM * 2;
    float* el = (float*)ws;      ws += (size_t)N_NODES * HEADS * 4;
    float* er = (float*)ws;      ws += (size_t)N_NODES * HEADS * 4;
    int* counts = (int*)ws;      ws += (size_t)N_NODES * 4;
    int* row_ptr = (int*)ws;     ws += (size_t)(N_NODES + 4) * 4;
    int* wptr = (int*)ws;        ws += (size_t)N_NODES * 4;
    int* src_sorted = (int*)ws;  ws += (size_t)N_EDGES * 4;
    int* flag = (int*)ws;        ws += 256;

    u16* h1 = (u16*)d_out;   // layer-1 output parked in d_out as bf16 (fits both dtypes)

    detect_dtype<<<1, 256, 0, stream>>>((const unsigned int*)data, flag);

    zero_i32<<<(N_NODES + 255) / 256, 256, 0, stream>>>(counts, N_NODES);
    hist_kernel<<<(N_EDGES + 255) / 256, 256, 0, stream>>>(dst, counts, N_EDGES);
    scan_kernel<<<1, 1024, 0, stream>>>(counts, row_ptr, wptr, N_NODES);
    scatter_kernel<<<(N_EDGES + 255) / 256, 256, 0, stream>>>(src, dst, wptr, src_sorted, N_EDGES);

    const int gemm_blocks = (N_NODES + 63) / 64;
    const int elr_blocks = (N_NODES * HEADS + 255) / 256;

    // layer 1
    gemm_bf16<<<gemm_blocks, 256, 0, stream>>>(data, W1, feat, N_NODES, 2, 2, flag);
    elr_kernel<<<elr_blocks, 256, 0, stream>>>(feat, al1, ar1, el, er, N_NODES, flag);
    aggregate_kernel<<<N_NODES, 256, 0, stream>>>(feat, el, er, b1, row_ptr, src_sorted,
                                                  (void*)h1, N_NODES, 0, flag);

    // layer 2
    gemm_bf16<<<gemm_blocks, 256, 0, stream>>>(h1, W2, feat, N_NODES, 0, 2, flag);
    elr_kernel<<<elr_blocks, 256, 0, stream>>>(feat, al2, ar2, el, er, N_NODES, flag);
    aggregate_kernel<<<N_NODES, 256, 0, stream>>>(feat, el, er, b2, row_ptr, src_sorted,
                                                  d_out, N_NODES, 2, flag);
}

// Round 5
// 470.472 us; speedup vs baseline: 2.2963x; 2.2963x over previous
//
#include <hip/hip_runtime.h>

#define N_NODES 50000
#define N_EDGES 800000
#define DIM 256
#define HEADS 8
#define HEAD_DIM 32
#define NEG_SLOPE 0.2f

typedef unsigned short u16;
typedef float floatx4 __attribute__((ext_vector_type(4)));
typedef __bf16 bf16x8 __attribute__((ext_vector_type(8)));

__device__ __forceinline__ float b2f(u16 u) {
    union { unsigned int i; float f; } v; v.i = ((unsigned int)u) << 16; return v.f;
}
__device__ __forceinline__ u16 f2b(float f) {
    union { float f; unsigned int i; } v; v.f = f;
    unsigned int x = v.i;
    if ((x & 0x7f800000u) == 0x7f800000u && (x & 0x007fffffu)) {
        return (u16)((x >> 16) | 0x0040u);
    }
    unsigned int r = (x + 0x7fffu + ((x >> 16) & 1u)) >> 16;
    return (u16)r;
}

// ---------------- dtype detection (proven in R4: picks fp32) ----------------
__global__ __launch_bounds__(256) void detect_dtype(const unsigned int* __restrict__ d,
                                                    int* __restrict__ flag) {
    __shared__ int cnt;
    if (threadIdx.x == 0) cnt = 0;
    __syncthreads();
    unsigned int w = d[threadIdx.x];
    int bad = 0;
    #pragma unroll
    for (int half = 0; half < 2; ++half) {
        u16 u = (u16)(w >> (16 * half));
        unsigned int e = (u >> 7) & 0xFFu;
        if (u != 0 && (e >= 141u || e <= 27u)) bad = 1;
    }
    atomicAdd(&cnt, bad);
    __syncthreads();
    if (threadIdx.x == 0) *flag = (cnt > 64) ? 1 : 0;   // 1 = fp32 inputs
}

__global__ __launch_bounds__(256) void fill_u32(unsigned int* __restrict__ p,
                                                unsigned int v, int n) {
    int i = blockIdx.x * 256 + threadIdx.x;
    if (i < n) p[i] = v;
}

// ---------------- CSR build ----------------
__global__ __launch_bounds__(256) void zero_i32(int* __restrict__ p, int n) {
    int i = blockIdx.x * 256 + threadIdx.x;
    if (i < n) p[i] = 0;
}

__global__ __launch_bounds__(256) void hist_kernel(const int* __restrict__ dst,
                                                   int* __restrict__ counts, int E) {
    int i = blockIdx.x * 256 + threadIdx.x;
    if (i < E) atomicAdd(&counts[dst[i]], 1);
}

// ---- multi-block exclusive scan over counts[n]: 1024 elems/block ----
__global__ __launch_bounds__(256) void scan_partial(const int* __restrict__ counts,
                                                    int* __restrict__ partial, int n) {
    int b = blockIdx.x, tid = threadIdx.x;
    int base = b * 1024 + tid * 4;
    int s = 0;
    #pragma unroll
    for (int k = 0; k < 4; ++k) if (base + k < n) s += counts[base + k];
    int lane = tid & 63;
    #pragma unroll
    for (int off = 32; off; off >>= 1) s += __shfl_xor(s, off);
    __shared__ int wsum[4];
    if (lane == 0) wsum[tid >> 6] = s;
    __syncthreads();
    if (tid == 0) partial[b] = wsum[0] + wsum[1] + wsum[2] + wsum[3];
}

__global__ __launch_bounds__(64) void scan_offsets(const int* __restrict__ partial,
                                                   int* __restrict__ offsets,
                                                   int* __restrict__ row_ptr,
                                                   int nb, int n) {
    int t = threadIdx.x;
    int v0 = (t < nb) ? partial[t] : 0;
    int v = v0;
    #pragma unroll
    for (int d = 1; d < 64; d <<= 1) {
        int u = __shfl_up(v, d);
        if (t >= d) v += u;
    }
    if (t < nb) offsets[t] = v - v0;     // exclusive
    if (t == 63) row_ptr[n] = v;         // grand total
}

__global__ __launch_bounds__(256) void scan_write(const int* __restrict__ counts,
                                                  const int* __restrict__ offsets,
                                                  int* __restrict__ row_ptr,
                                                  int* __restrict__ wptr, int n) {
    int b = blockIdx.x, tid = threadIdx.x;
    int base = b * 1024 + tid * 4;
    int v[4]; int s = 0;
    #pragma unroll
    for (int k = 0; k < 4; ++k) { v[k] = (base + k < n) ? counts[base + k] : 0; s += v[k]; }
    int lane = tid & 63, w = tid >> 6;
    int incl = s;
    #pragma unroll
    for (int d = 1; d < 64; d <<= 1) {
        int u = __shfl_up(incl, d);
        if (lane >= d) incl += u;
    }
    __shared__ int wsum[4];
    if (lane == 63) wsum[w] = incl;
    __syncthreads();
    int woff = 0;
    for (int i = 0; i < w; ++i) woff += wsum[i];
    int run = offsets[b] + woff + incl - s;
    #pragma unroll
    for (int k = 0; k < 4; ++k) {
        if (base + k < n) { row_ptr[base + k] = run; wptr[base + k] = run; run += v[k]; }
    }
}

__global__ __launch_bounds__(256) void scatter_kernel(const int* __restrict__ src,
                                                      const int* __restrict__ dst,
                                                      int* __restrict__ wptr,
                                                      int* __restrict__ src_sorted, int E) {
    int i = blockIdx.x * 256 + threadIdx.x;
    if (i < E) {
        int pos = atomicAdd(&wptr[dst[i]], 1);
        src_sorted[pos] = src[i];
    }
}

// ---- W transpose + bf16 convert: Wt[n][k] = bf16(W[k][n]) ----
__global__ __launch_bounds__(256) void transpose_w(const void* __restrict__ W,
                                                   u16* __restrict__ Wt,
                                                   const int* __restrict__ flagp) {
    const int isf = *flagp;
    int k = blockIdx.x;
    int n = threadIdx.x;
    float v = isf ? ((const float*)W)[k * 256 + n] : b2f(((const u16*)W)[k * 256 + n]);
    Wt[n * 256 + k] = f2b(v);
}

// ---- GEMM: out[M,256](bf16) = A[M,256] @ W ; A adaptive, B from Wt(bf16) ----
#define LDA 264
#define LDB 40

__global__ __launch_bounds__(256, 2) void gemm_bf16(const void* __restrict__ A,
                                                    const u16* __restrict__ Wt,
                                                    u16* __restrict__ out, int M,
                                                    int a_mode,
                                                    const int* __restrict__ flagp) {
    __shared__ u16 As[64][LDA];
    __shared__ u16 Ws[256][LDB];
    const int tid  = threadIdx.x;
    const int wave = tid >> 6;
    const int lane = tid & 63;
    const int quad = lane >> 4;
    const int l16  = lane & 15;
    const int m0   = blockIdx.x * 64;
    const bool a_fp32 = (a_mode == 2) && (*flagp != 0);

    #pragma unroll
    for (int it = 0; it < 8; ++it) {
        int idx = it * 256 + tid;
        int r = idx >> 5;
        int c = (idx & 31) << 3;
        int gr = m0 + r;
        if (gr < M) {
            if (a_fp32) {
                const float* Af = (const float*)A;
                float4 f0 = *(const float4*)(Af + gr * 256 + c);
                float4 f1 = *(const float4*)(Af + gr * 256 + c + 4);
                As[r][c + 0] = f2b(f0.x); As[r][c + 1] = f2b(f0.y);
                As[r][c + 2] = f2b(f0.z); As[r][c + 3] = f2b(f0.w);
                As[r][c + 4] = f2b(f1.x); As[r][c + 5] = f2b(f1.y);
                As[r][c + 6] = f2b(f1.z); As[r][c + 7] = f2b(f1.w);
            } else {
                *(uint4*)&As[r][c] = *(const uint4*)((const u16*)A + gr * 256 + c);
            }
        } else {
            uint4 z = {0u, 0u, 0u, 0u};
            *(uint4*)&As[r][c] = z;
        }
    }

    floatx4 acc[16] = {};

    for (int s = 0; s < 8; ++s) {
        const int k0 = s * 32;
        __syncthreads();
        // stage Ws[n][kk] = Wt[n][k0+kk] : pure vec8 copies
        #pragma unroll
        for (int it = 0; it < 4; ++it) {
            int idx = it * 256 + tid;
            int n = idx >> 2;
            int k8 = (idx & 3) << 3;
            *(uint4*)&Ws[n][k8] = *(const uint4*)(Wt + n * 256 + k0 + k8);
        }
        __syncthreads();

        bf16x8 afrag = *(const bf16x8*)&As[wave * 16 + l16][k0 + quad * 8];
        #pragma unroll
        for (int t = 0; t < 16; ++t) {
            bf16x8 bfrag = *(const bf16x8*)&Ws[t * 16 + l16][quad * 8];
            acc[t] = __builtin_amdgcn_mfma_f32_16x16x32_bf16(afrag, bfrag, acc[t], 0, 0, 0);
        }
    }

    #pragma unroll
    for (int t = 0; t < 16; ++t) {
        #pragma unroll
        for (int r = 0; r < 4; ++r) {
            int grow = m0 + wave * 16 + quad * 4 + r;
            if (grow < M) out[grow * 256 + t * 16 + l16] = f2b(acc[t][r]);
        }
    }
}

// ---------------- el/er per (node, head), vectorized ----------------
__global__ __launch_bounds__(256) void elr_kernel(const u16* __restrict__ feat,
                                                  const void* __restrict__ al,
                                                  const void* __restrict__ ar,
                                                  float* __restrict__ el,
                                                  float* __restrict__ er, int N,
                                                  const int* __restrict__ flagp) {
    __shared__ float al_s[256], ar_s[256];
    const int isf = *flagp;
    int tid = threadIdx.x;
    al_s[tid] = isf ? ((const float*)al)[tid] : b2f(((const u16*)al)[tid]);
    ar_s[tid] = isf ? ((const float*)ar)[tid] : b2f(((const u16*)ar)[tid]);
    __syncthreads();
    int gid = blockIdx.x * 256 + tid;
    if (gid >= N * HEADS) return;
    int n = gid >> 3, h = gid & 7;
    const u16* f = feat + n * DIM + h * HEAD_DIM;
    float sl = 0.f, sr = 0.f;
    #pragma unroll
    for (int q = 0; q < 4; ++q) {
        uint4 u = *(const uint4*)(f + q * 8);
        unsigned int ww[4] = {u.x, u.y, u.z, u.w};
        #pragma unroll
        for (int p = 0; p < 4; ++p) {
            float v0 = b2f((u16)(ww[p] & 0xffffu));
            float v1 = b2f((u16)(ww[p] >> 16));
            int d = q * 8 + p * 2;
            sl += v0 * al_s[h * 32 + d]     + v1 * al_s[h * 32 + d + 1];
            sr += v0 * ar_s[h * 32 + d]     + v1 * ar_s[h * 32 + d + 1];
        }
    }
    el[gid] = sl;
    er[gid] = sr;
}

// ---------------- aggregate: ONE WAVE PER NODE, shuffle-only ----------------
// lane l: head h = l>>3, sub j = l&7 (phase 1 / alpha); dims 4l..4l+3 (phase 2)
__global__ __launch_bounds__(256) void aggregate_kernel(const u16* __restrict__ feat,
                                                        const float* __restrict__ el,
                                                        const float* __restrict__ er,
                                                        const void* __restrict__ bias,
                                                        const int* __restrict__ row_ptr,
                                                        const int* __restrict__ src_sorted,
                                                        void* __restrict__ out, int N,
                                                        int out_mode,
                                                        const int* __restrict__ flagp) {
    const int isf = *flagp;
    const int lane = threadIdx.x & 63;
    const int node = blockIdx.x * 4 + (threadIdx.x >> 6);
    if (node >= N) return;
    const int h = lane >> 3;
    const int j = lane & 7;
    const int beg = row_ptr[node];
    const int deg = row_ptr[node + 1] - beg;

    const float ern = er[node * HEADS + h];

    // phase 1a: per-head max (8 lanes stride edges)
    float mx = -__builtin_inff();
    for (int i = j; i < deg; i += 8) {
        int s = src_sorted[beg + i];
        float e = el[s * HEADS + h] + ern;
        e = e > 0.f ? e : NEG_SLOPE * e;
        mx = fmaxf(mx, e);
    }
    mx = fmaxf(mx, __shfl_xor(mx, 1));
    mx = fmaxf(mx, __shfl_xor(mx, 2));
    mx = fmaxf(mx, __shfl_xor(mx, 4));

    // phase 1b: per-head sum of exp
    float sm = 0.f;
    for (int i = j; i < deg; i += 8) {
        int s = src_sorted[beg + i];
        float e = el[s * HEADS + h] + ern;
        e = e > 0.f ? e : NEG_SLOPE * e;
        sm += __expf(e - mx);
    }
    sm += __shfl_xor(sm, 1);
    sm += __shfl_xor(sm, 2);
    sm += __shfl_xor(sm, 4);
    const float inv = sm > 0.f ? 1.f / sm : 0.f;

    // phase 2: chunks of 8 edges; lane computes alpha(edge=j, head=h), then
    // the wave sweeps the 8 edges reading full 512B feat rows (uint2/lane)
    float a0 = 0.f, a1 = 0.f, a2 = 0.f, a3 = 0.f;
    for (int c0 = 0; c0 < deg; c0 += 8) {
        int i = c0 + j;
        int s = 0; float al_ = 0.f;
        if (i < deg) {
            s = src_sorted[beg + i];
            float e = el[s * HEADS + h] + ern;
            e = e > 0.f ? e : NEG_SLOPE * e;
            al_ = __expf(e - mx) * inv;
        }
        int rem = deg - c0; if (rem > 8) rem = 8;
        for (int e8 = 0; e8 < rem; ++e8) {
            int   se = __shfl(s,   h * 8 + e8);
            float ae = __shfl(al_, h * 8 + e8);
            uint2 f = *(const uint2*)(feat + se * DIM + 4 * lane);
            a0 += ae * b2f((u16)(f.x & 0xffffu));
            a1 += ae * b2f((u16)(f.x >> 16));
            a2 += ae * b2f((u16)(f.y & 0xffffu));
            a3 += ae * b2f((u16)(f.y >> 16));
        }
    }

    float b0, b1v, b2v, b3;
    if (isf) {
        float4 bv = *(const float4*)((const float*)bias + 4 * lane);
        b0 = bv.x; b1v = bv.y; b2v = bv.z; b3 = bv.w;
    } else {
        uint2 bu = *(const uint2*)((const u16*)bias + 4 * lane);
        b0 = b2f((u16)(bu.x & 0xffffu)); b1v = b2f((u16)(bu.x >> 16));
        b2v = b2f((u16)(bu.y & 0xffffu)); b3 = b2f((u16)(bu.y >> 16));
    }
    float o0 = fmaxf(a0 + b0, 0.f), o1 = fmaxf(a1 + b1v, 0.f);
    float o2 = fmaxf(a2 + b2v, 0.f), o3 = fmaxf(a3 + b3, 0.f);

    if (out_mode == 0 || !isf) {
        uint2 pk;
        pk.x = (unsigned int)f2b(o0) | ((unsigned int)f2b(o1) << 16);
        pk.y = (unsigned int)f2b(o2) | ((unsigned int)f2b(o3) << 16);
        *(uint2*)((u16*)out + node * DIM + 4 * lane) = pk;
    } else {
        float4 ov = {o0, o1, o2, o3};
        *(float4*)((float*)out + node * DIM + 4 * lane) = ov;
    }
}

// ---------------- launch ----------------

extern "C" void kernel_launch(void* const* d_in, const int* in_sizes, int n_in,
                              void* d_out, int out_size, void* d_ws, size_t ws_size,
                              hipStream_t stream) {
    const void* data = d_in[0];
    const int* src = (const int*)d_in[1];
    const int* dst = (const int*)d_in[2];
    const void* W1  = d_in[3];
    const void* al1 = d_in[4];
    const void* ar1 = d_in[5];
    const void* b1  = d_in[6];
    const void* W2  = d_in[7];
    const void* al2 = d_in[8];
    const void* ar2 = d_in[9];
    const void* b2  = d_in[10];

    const size_t NEEDED =
        (size_t)N_NODES * DIM * 2 +        // feat (bf16)
        (size_t)N_NODES * HEADS * 4 * 2 +  // el + er
        (size_t)N_NODES * 4 * 2 +          // counts, wptr (recycled as Wt1/Wt2)
        (size_t)(N_NODES + 4) * 4 +        // row_ptr
        (size_t)N_EDGES * 4 +              // src_sorted
        1024;                              // partial/offsets/flag

    if (ws_size < NEEDED) {
        int nwords = (out_size + 1) / 2;
        fill_u32<<<(nwords + 255) / 256, 256, 0, stream>>>(
            (unsigned int*)d_out, 0x42C842C8u, nwords);
        return;
    }

    char* ws = (char*)d_ws;
    u16* feat = (u16*)ws;        ws += (size_t)N_NODES * DIM * 2;
    float* el = (float*)ws;      ws += (size_t)N_NODES * HEADS * 4;
    float* er = (float*)ws;      ws += (size_t)N_NODES * HEADS * 4;
    int* counts = (int*)ws;      ws += (size_t)N_NODES * 4;   // -> Wt1 after scatter
    int* wptr = (int*)ws;        ws += (size_t)N_NODES * 4;   // -> Wt2 after scatter
    int* row_ptr = (int*)ws;     ws += (size_t)(N_NODES + 4) * 4;
    int* src_sorted = (int*)ws;  ws += (size_t)N_EDGES * 4;
    int* partial = (int*)ws;     ws += 256;
    int* offsets = (int*)ws;     ws += 256;
    int* flag = (int*)ws;        ws += 256;

    u16* Wt1 = (u16*)counts;     // 131072 B each, fits in 200000 B regions
    u16* Wt2 = (u16*)wptr;
    u16* h1 = (u16*)d_out;       // layer-1 activations parked in d_out (bf16)

    const int nb = (N_NODES + 1023) / 1024;   // 49

    detect_dtype<<<1, 256, 0, stream>>>((const unsigned int*)data, flag);

    zero_i32<<<(N_NODES + 255) / 256, 256, 0, stream>>>(counts, N_NODES);
    hist_kernel<<<(N_EDGES + 255) / 256, 256, 0, stream>>>(dst, counts, N_EDGES);
    scan_partial<<<nb, 256, 0, stream>>>(counts, partial, N_NODES);
    scan_offsets<<<1, 64, 0, stream>>>(partial, offsets, row_ptr, nb, N_NODES);
    scan_write<<<nb, 256, 0, stream>>>(counts, offsets, row_ptr, wptr, N_NODES);
    scatter_kernel<<<(N_EDGES + 255) / 256, 256, 0, stream>>>(src, dst, wptr, src_sorted, N_EDGES);

    // counts/wptr dead -> reuse as Wt1/Wt2
    transpose_w<<<256, 256, 0, stream>>>(W1, Wt1, flag);
    transpose_w<<<256, 256, 0, stream>>>(W2, Wt2, flag);

    const int gemm_blocks = (N_NODES + 63) / 64;
    const int elr_blocks = (N_NODES * HEADS + 255) / 256;
    const int agg_blocks = (N_NODES + 3) / 4;

    // layer 1
    gemm_bf16<<<gemm_blocks, 256, 0, stream>>>(data, Wt1, feat, N_NODES, 2, flag);
    elr_kernel<<<elr_blocks, 256, 0, stream>>>(feat, al1, ar1, el, er, N_NODES, flag);
    aggregate_kernel<<<agg_blocks, 256, 0, stream>>>(feat, el, er, b1, row_ptr, src_sorted,
                                                     (void*)h1, N_NODES, 0, flag);

    // layer 2
    gemm_bf16<<<gemm_blocks, 256, 0, stream>>>(h1, Wt2, feat, N_NODES, 0, flag);
    elr_kernel<<<elr_blocks, 256, 0, stream>>>(feat, al2, ar2, el, er, N_NODES, flag);
    aggregate_kernel<<<agg_blocks, 256, 0, stream>>>(feat, el, er, b2, row_ptr, src_sorted,
                                                     d_out, N_NODES, 2, flag);
}

// Round 6
// 439.911 us; speedup vs baseline: 2.4559x; 1.0695x over previous
//
#include <hip/hip_runtime.h>

#define N_NODES 50000
#define N_EDGES 800000
#define DIM 256
#define HEADS 8
#define NEG_SLOPE 0.2f

typedef unsigned short u16;
typedef float floatx4 __attribute__((ext_vector_type(4)));
typedef __bf16 bf16x8 __attribute__((ext_vector_type(8)));

__device__ __forceinline__ float b2f(u16 u) {
    union { unsigned int i; float f; } v; v.i = ((unsigned int)u) << 16; return v.f;
}
__device__ __forceinline__ u16 f2b(float f) {
    union { float f; unsigned int i; } v; v.f = f;
    unsigned int x = v.i;
    if ((x & 0x7f800000u) == 0x7f800000u && (x & 0x007fffffu)) {
        return (u16)((x >> 16) | 0x0040u);
    }
    unsigned int r = (x + 0x7fffu + ((x >> 16) & 1u)) >> 16;
    return (u16)r;
}

__global__ __launch_bounds__(256) void fill_u32(unsigned int* __restrict__ p,
                                                unsigned int v, int n) {
    int i = blockIdx.x * 256 + threadIdx.x;
    if (i < n) p[i] = v;
}

// ---- init: zero counts everywhere; block 0 additionally detects dtype ----
__global__ __launch_bounds__(256) void init_kernel(const unsigned int* __restrict__ d,
                                                   int* __restrict__ counts,
                                                   int* __restrict__ flag) {
    int i = blockIdx.x * 256 + threadIdx.x;
    if (i < N_NODES) counts[i] = 0;
    if (blockIdx.x == 0) {
        __shared__ int cnt;
        if (threadIdx.x == 0) cnt = 0;
        __syncthreads();
        unsigned int w = d[threadIdx.x];
        int bad = 0;
        #pragma unroll
        for (int half = 0; half < 2; ++half) {
            u16 u = (u16)(w >> (16 * half));
            unsigned int e = (u >> 7) & 0xFFu;
            if (u != 0 && (e >= 141u || e <= 27u)) bad = 1;
        }
        atomicAdd(&cnt, bad);
        __syncthreads();
        if (threadIdx.x == 0) *flag = (cnt > 64) ? 1 : 0;   // 1 = fp32 inputs
    }
}

// ---- prep: blocks 0..31 = LDS-tiled W1/W2 transpose->bf16; rest = data->bf16 ----
__global__ __launch_bounds__(256) void prep_kernel(const void* __restrict__ W1,
                                                   const void* __restrict__ W2,
                                                   const void* __restrict__ data,
                                                   u16* __restrict__ Wt1,
                                                   u16* __restrict__ Wt2,
                                                   u16* __restrict__ datab,
                                                   const int* __restrict__ flagp) {
    const int isf = *flagp;
    int b = blockIdx.x;
    if (b < 32) {
        const void* W = (b < 16) ? W1 : W2;
        u16* Wt = (b < 16) ? Wt1 : Wt2;
        int t = b & 15;
        int k0 = (t >> 2) * 64, n0 = (t & 3) * 64;
        __shared__ float lt[64][65];
        int c = threadIdx.x & 63, r0 = threadIdx.x >> 6;
        #pragma unroll
        for (int j = 0; j < 16; ++j) {
            int r = j * 4 + r0;
            lt[r][c] = isf ? ((const float*)W)[(k0 + r) * 256 + n0 + c]
                           : b2f(((const u16*)W)[(k0 + r) * 256 + n0 + c]);
        }
        __syncthreads();
        #pragma unroll
        for (int j = 0; j < 16; ++j) {
            int rn = j * 4 + r0;
            Wt[(n0 + rn) * 256 + k0 + c] = f2b(lt[c][rn]);   // Wt[n][k]=W[k][n]
        }
    } else {
        if (!isf) return;   // data already bf16; GEMM reads it directly
        int base = (b - 32) * 2048 + threadIdx.x * 8;
        const float* df = (const float*)data + base;
        float4 f0 = *(const float4*)df;
        float4 f1 = *(const float4*)(df + 4);
        u16 tb[8] = {f2b(f0.x), f2b(f0.y), f2b(f0.z), f2b(f0.w),
                     f2b(f1.x), f2b(f1.y), f2b(f1.z), f2b(f1.w)};
        *(uint4*)(datab + base) = *(uint4*)tb;
    }
}

// ---------------- CSR build ----------------
__global__ __launch_bounds__(256) void hist_kernel(const int* __restrict__ dst,
                                                   int* __restrict__ counts, int E) {
    int i = blockIdx.x * 256 + threadIdx.x;
    if (i < E) atomicAdd(&counts[dst[i]], 1);
}

__global__ __launch_bounds__(256) void scan_partial(const int* __restrict__ counts,
                                                    int* __restrict__ partial, int n) {
    int b = blockIdx.x, tid = threadIdx.x;
    int base = b * 1024 + tid * 4;
    int s = 0;
    #pragma unroll
    for (int k = 0; k < 4; ++k) if (base + k < n) s += counts[base + k];
    int lane = tid & 63;
    #pragma unroll
    for (int off = 32; off; off >>= 1) s += __shfl_xor(s, off);
    __shared__ int wsum[4];
    if (lane == 0) wsum[tid >> 6] = s;
    __syncthreads();
    if (tid == 0) partial[b] = wsum[0] + wsum[1] + wsum[2] + wsum[3];
}

__global__ __launch_bounds__(64) void scan_offsets(const int* __restrict__ partial,
                                                   int* __restrict__ offsets,
                                                   int* __restrict__ row_ptr,
                                                   int nb, int n) {
    int t = threadIdx.x;
    int v0 = (t < nb) ? partial[t] : 0;
    int v = v0;
    #pragma unroll
    for (int d = 1; d < 64; d <<= 1) {
        int u = __shfl_up(v, d);
        if (t >= d) v += u;
    }
    if (t < nb) offsets[t] = v - v0;
    if (t == 63) row_ptr[n] = v;
}

__global__ __launch_bounds__(256) void scan_write(const int* __restrict__ counts,
                                                  const int* __restrict__ offsets,
                                                  int* __restrict__ row_ptr,
                                                  int* __restrict__ wptr, int n) {
    int b = blockIdx.x, tid = threadIdx.x;
    int base = b * 1024 + tid * 4;
    int v[4]; int s = 0;
    #pragma unroll
    for (int k = 0; k < 4; ++k) { v[k] = (base + k < n) ? counts[base + k] : 0; s += v[k]; }
    int lane = tid & 63, w = tid >> 6;
    int incl = s;
    #pragma unroll
    for (int d = 1; d < 64; d <<= 1) {
        int u = __shfl_up(incl, d);
        if (lane >= d) incl += u;
    }
    __shared__ int wsum[4];
    if (lane == 63) wsum[w] = incl;
    __syncthreads();
    int woff = 0;
    for (int i = 0; i < w; ++i) woff += wsum[i];
    int run = offsets[b] + woff + incl - s;
    #pragma unroll
    for (int k = 0; k < 4; ++k) {
        if (base + k < n) { row_ptr[base + k] = run; wptr[base + k] = run; run += v[k]; }
    }
}

__global__ __launch_bounds__(256) void scatter_kernel(const int* __restrict__ src,
                                                      const int* __restrict__ dst,
                                                      int* __restrict__ wptr,
                                                      int* __restrict__ src_sorted, int E) {
    int i = blockIdx.x * 256 + threadIdx.x;
    if (i < E) {
        int pos = atomicAdd(&wptr[dst[i]], 1);
        src_sorted[pos] = src[i];
    }
}

// ---- GEMM (bf16 MFMA) + fused el/er epilogue ----
// waves own n-quarters: per K-step 4 A-frags + 4 B-frags, 16 MFMA
#define LDA 264
#define LDB 40

__global__ __launch_bounds__(256, 2) void gemm_fused(const u16* __restrict__ Aisf,
                                                     const u16* __restrict__ Abf,
                                                     const u16* __restrict__ Wt,
                                                     u16* __restrict__ outF,
                                                     float* __restrict__ el,
                                                     float* __restrict__ er,
                                                     const void* __restrict__ al,
                                                     const void* __restrict__ ar,
                                                     int M, const int* __restrict__ flagp) {
    const int isf = *flagp;
    const u16* A = isf ? Aisf : Abf;
    __shared__ u16 As[64][LDA];
    __shared__ u16 Ws[256][LDB];
    const int tid  = threadIdx.x;
    const int w    = tid >> 6;       // wave: n-quarter
    const int lane = tid & 63;
    const int quad = lane >> 4;
    const int l16  = lane & 15;
    const int m0   = blockIdx.x * 64;

    #pragma unroll
    for (int it = 0; it < 8; ++it) {
        int idx = it * 256 + tid;
        int r = idx >> 5;
        int c = (idx & 31) << 3;
        int gr = m0 + r;
        if (gr < M) {
            *(uint4*)&As[r][c] = *(const uint4*)(A + gr * 256 + c);
        } else {
            uint4 z = {0u, 0u, 0u, 0u};
            *(uint4*)&As[r][c] = z;
        }
    }

    floatx4 acc[4][4] = {};

    for (int s = 0; s < 8; ++s) {
        __syncthreads();
        #pragma unroll
        for (int it = 0; it < 4; ++it) {
            int idx = it * 256 + tid;
            int n = idx >> 2;
            int k8 = (idx & 3) << 3;
            *(uint4*)&Ws[n][k8] = *(const uint4*)(Wt + n * 256 + s * 32 + k8);
        }
        __syncthreads();

        bf16x8 af[4], bfv[4];
        #pragma unroll
        for (int i = 0; i < 4; ++i)
            af[i] = *(const bf16x8*)&As[16 * i + l16][s * 32 + quad * 8];
        #pragma unroll
        for (int t = 0; t < 4; ++t)
            bfv[t] = *(const bf16x8*)&Ws[64 * w + 16 * t + l16][quad * 8];
        #pragma unroll
        for (int i = 0; i < 4; ++i)
            #pragma unroll
            for (int t = 0; t < 4; ++t)
                acc[i][t] = __builtin_amdgcn_mfma_f32_16x16x32_bf16(af[i], bfv[t], acc[i][t], 0, 0, 0);
    }

    // C/D: col = l16, row = quad*4+r (within 16x16 slice)
    #pragma unroll
    for (int i = 0; i < 4; ++i)
        #pragma unroll
        for (int t = 0; t < 4; ++t)
            #pragma unroll
            for (int r = 0; r < 4; ++r) {
                int row = m0 + 16 * i + quad * 4 + r;
                if (row < M) outF[row * 256 + 64 * w + 16 * t + l16] = f2b(acc[i][t][r]);
            }

    // fused el/er: wave w covers heads 2w, 2w+1
    float alv[4], arv[4];
    #pragma unroll
    for (int t = 0; t < 4; ++t) {
        int c = 64 * w + 16 * t + l16;
        alv[t] = isf ? ((const float*)al)[c] : b2f(((const u16*)al)[c]);
        arv[t] = isf ? ((const float*)ar)[c] : b2f(((const u16*)ar)[c]);
    }
    #pragma unroll
    for (int i = 0; i < 4; ++i)
        #pragma unroll
        for (int r = 0; r < 4; ++r) {
            int row = m0 + 16 * i + quad * 4 + r;
            #pragma unroll
            for (int tt = 0; tt < 2; ++tt) {
                float pl = acc[i][2 * tt][r] * alv[2 * tt] + acc[i][2 * tt + 1][r] * alv[2 * tt + 1];
                float pr = acc[i][2 * tt][r] * arv[2 * tt] + acc[i][2 * tt + 1][r] * arv[2 * tt + 1];
                #pragma unroll
                for (int mask = 1; mask <= 8; mask <<= 1) {
                    pl += __shfl_xor(pl, mask);
                    pr += __shfl_xor(pr, mask);
                }
                if (l16 == 0 && row < M) {
                    el[row * 8 + 2 * w + tt] = pl;
                    er[row * 8 + 2 * w + tt] = pr;
                }
            }
        }
}

// ---- aggregate: 1 wave/node, online softmax + half-wave uint4 sweep ----
__global__ __launch_bounds__(256) void aggregate_kernel(const u16* __restrict__ feat,
                                                        const float* __restrict__ el,
                                                        const float* __restrict__ er,
                                                        const void* __restrict__ bias,
                                                        const int* __restrict__ row_ptr,
                                                        const int* __restrict__ src_sorted,
                                                        void* __restrict__ out,
                                                        int out_mode,
                                                        const int* __restrict__ flagp) {
    const int isf = *flagp;
    const int lane = threadIdx.x & 63;
    const int node = blockIdx.x * 4 + (threadIdx.x >> 6);
    if (node >= N_NODES) return;
    const int h = lane >> 3;
    const int j = lane & 7;
    const int beg = row_ptr[node];
    const int deg = row_ptr[node + 1] - beg;
    const float ern = er[node * HEADS + h];

    // online softmax over this head's edges (8 lanes stride)
    float m = -1e30f, ssum = 0.f;
    for (int i = j; i < deg; i += 8) {
        int s = src_sorted[beg + i];
        float e = el[s * 8 + h] + ern;
        e = e > 0.f ? e : NEG_SLOPE * e;
        float mn = fmaxf(m, e);
        ssum = ssum * __expf(m - mn) + __expf(e - mn);
        m = mn;
    }
    #pragma unroll
    for (int mask = 1; mask <= 4; mask <<= 1) {
        float mo = __shfl_xor(m, mask);
        float so = __shfl_xor(ssum, mask);
        float mn = fmaxf(m, mo);
        ssum = ssum * __expf(m - mn) + so * __expf(mo - mn);
        m = mn;
    }
    const float mx = m;
    const float inv = ssum > 0.f ? 1.f / ssum : 0.f;

    // phase 2: chunks of 8 edges; halves sweep 2 rows/iter with uint4 loads
    const int q = lane & 31;       // owns dims 8q..8q+7
    const int half = lane >> 5;
    const int hq = q >> 2;         // head of owned dims
    float a[8] = {};
    for (int c0 = 0; c0 < deg; c0 += 8) {
        int i = c0 + j;
        int s = 0; float av = 0.f;
        if (i < deg) {
            s = src_sorted[beg + i];
            float e = el[s * 8 + h] + ern;
            e = e > 0.f ? e : NEG_SLOPE * e;
            av = __expf(e - mx) * inv;
        }
        int rem = deg - c0; if (rem > 8) rem = 8;
        for (int t2 = 0; t2 < rem; t2 += 2) {
            int sel = hq * 8 + t2 + half;   // out-of-range edge -> av=0 lane, contributes 0
            int   se = __shfl(s, sel);
            float ae = __shfl(av, sel);
            uint4 f = *(const uint4*)(feat + se * DIM + 8 * q);
            a[0] += ae * b2f((u16)(f.x & 0xffffu)); a[1] += ae * b2f((u16)(f.x >> 16));
            a[2] += ae * b2f((u16)(f.y & 0xffffu)); a[3] += ae * b2f((u16)(f.y >> 16));
            a[4] += ae * b2f((u16)(f.z & 0xffffu)); a[5] += ae * b2f((u16)(f.z >> 16));
            a[6] += ae * b2f((u16)(f.w & 0xffffu)); a[7] += ae * b2f((u16)(f.w >> 16));
        }
    }
    #pragma unroll
    for (int k = 0; k < 8; ++k) a[k] += __shfl_xor(a[k], 32);

    if (half == 0) {
        float o[8];
        if (isf) {
            float4 b0 = *(const float4*)((const float*)bias + 8 * q);
            float4 b1 = *(const float4*)((const float*)bias + 8 * q + 4);
            o[0] = a[0] + b0.x; o[1] = a[1] + b0.y; o[2] = a[2] + b0.z; o[3] = a[3] + b0.w;
            o[4] = a[4] + b1.x; o[5] = a[5] + b1.y; o[6] = a[6] + b1.z; o[7] = a[7] + b1.w;
        } else {
            uint4 bu = *(const uint4*)((const u16*)bias + 8 * q);
            o[0] = a[0] + b2f((u16)(bu.x & 0xffffu)); o[1] = a[1] + b2f((u16)(bu.x >> 16));
            o[2] = a[2] + b2f((u16)(bu.y & 0xffffu)); o[3] = a[3] + b2f((u16)(bu.y >> 16));
            o[4] = a[4] + b2f((u16)(bu.z & 0xffffu)); o[5] = a[5] + b2f((u16)(bu.z >> 16));
            o[6] = a[6] + b2f((u16)(bu.w & 0xffffu)); o[7] = a[7] + b2f((u16)(bu.w >> 16));
        }
        #pragma unroll
        for (int k = 0; k < 8; ++k) o[k] = fmaxf(o[k], 0.f);
        if (out_mode == 0 || !isf) {
            u16 pk[8] = {f2b(o[0]), f2b(o[1]), f2b(o[2]), f2b(o[3]),
                         f2b(o[4]), f2b(o[5]), f2b(o[6]), f2b(o[7])};
            *(uint4*)((u16*)out + node * DIM + 8 * q) = *(uint4*)pk;
        } else {
            float4 v0 = {o[0], o[1], o[2], o[3]};
            float4 v1 = {o[4], o[5], o[6], o[7]};
            *(float4*)((float*)out + node * DIM + 8 * q) = v0;
            *(float4*)((float*)out + node * DIM + 8 * q + 4) = v1;
        }
    }
}

// ---------------- launch ----------------
extern "C" void kernel_launch(void* const* d_in, const int* in_sizes, int n_in,
                              void* d_out, int out_size, void* d_ws, size_t ws_size,
                              hipStream_t stream) {
    const void* data = d_in[0];
    const int* src = (const int*)d_in[1];
    const int* dst = (const int*)d_in[2];
    const void* W1  = d_in[3];
    const void* al1 = d_in[4];
    const void* ar1 = d_in[5];
    const void* b1  = d_in[6];
    const void* W2  = d_in[7];
    const void* al2 = d_in[8];
    const void* ar2 = d_in[9];
    const void* b2  = d_in[10];

    const size_t NEEDED =
        (size_t)N_NODES * DIM * 2 +        // feat
        (size_t)N_NODES * HEADS * 4 * 2 +  // el, er
        (size_t)N_NODES * 4 * 2 +          // counts, wptr
        (size_t)(N_NODES + 4) * 4 +        // row_ptr
        (size_t)N_EDGES * 4 +              // src_sorted
        2 * 256 * 256 * 2 +                // Wt1, Wt2
        1024;

    if (ws_size < NEEDED) {
        int nwords = (out_size + 1) / 2;
        fill_u32<<<(nwords + 255) / 256, 256, 0, stream>>>(
            (unsigned int*)d_out, 0x42C842C8u, nwords);
        return;
    }

    char* ws = (char*)d_ws;
    u16* feat = (u16*)ws;        ws += (size_t)N_NODES * DIM * 2;
    float* el = (float*)ws;      ws += (size_t)N_NODES * HEADS * 4;
    float* er = (float*)ws;      ws += (size_t)N_NODES * HEADS * 4;
    int* counts = (int*)ws;      ws += (size_t)N_NODES * 4;
    int* wptr = (int*)ws;        ws += (size_t)N_NODES * 4;
    int* row_ptr = (int*)ws;     ws += (size_t)(N_NODES + 4) * 4;
    int* src_sorted = (int*)ws;  ws += (size_t)N_EDGES * 4;
    u16* Wt1 = (u16*)ws;         ws += 256 * 256 * 2;
    u16* Wt2 = (u16*)ws;         ws += 256 * 256 * 2;
    int* partial = (int*)ws;     ws += 256;
    int* offsets = (int*)ws;     ws += 256;
    int* flag = (int*)ws;        ws += 256;

    u16* h1    = (u16*)d_out;                          // layer-1 acts (bf16), first 25.6 MB
    u16* datab = (u16*)d_out + (size_t)N_NODES * DIM;  // bf16 data, second half (fp32 world only)

    const int nb = (N_NODES + 1023) / 1024;            // 49

    init_kernel<<<(N_NODES + 255) / 256, 256, 0, stream>>>(
        (const unsigned int*)data, counts, flag);
    prep_kernel<<<32 + (N_NODES * DIM) / 2048, 256, 0, stream>>>(
        W1, W2, data, Wt1, Wt2, datab, flag);
    hist_kernel<<<(N_EDGES + 255) / 256, 256, 0, stream>>>(dst, counts, N_EDGES);
    scan_partial<<<nb, 256, 0, stream>>>(counts, partial, N_NODES);
    scan_offsets<<<1, 64, 0, stream>>>(partial, offsets, row_ptr, nb, N_NODES);
    scan_write<<<nb, 256, 0, stream>>>(counts, offsets, row_ptr, wptr, N_NODES);
    scatter_kernel<<<(N_EDGES + 255) / 256, 256, 0, stream>>>(src, dst, wptr, src_sorted, N_EDGES);

    const int gemm_blocks = (N_NODES + 63) / 64;
    const int agg_blocks = (N_NODES + 3) / 4;

    gemm_fused<<<gemm_blocks, 256, 0, stream>>>(datab, (const u16*)data, Wt1, feat,
                                                el, er, al1, ar1, N_NODES, flag);
    aggregate_kernel<<<agg_blocks, 256, 0, stream>>>(feat, el, er, b1, row_ptr, src_sorted,
                                                     (void*)h1, 0, flag);
    gemm_fused<<<gemm_blocks, 256, 0, stream>>>(h1, h1, Wt2, feat,
                                                el, er, al2, ar2, N_NODES, flag);
    aggregate_kernel<<<agg_blocks, 256, 0, stream>>>(feat, el, er, b2, row_ptr, src_sorted,
                                                     d_out, 2, flag);
}